// Round 4
// baseline (260.695 us; speedup 1.0000x reference)
//
#include <hip/hip_runtime.h>

// Problem constants (B,C,H,W = 32,64,128,128)
static constexpr int Cc  = 64;
static constexpr int HWc = 16384;
static constexpr int Bc  = 32;

// ---------------------------------------------------------------------------
// Identity (verified R1/R2): A[b] = -0.5*theta exactly, so
//   out[b,n,:] = W_lin @ relu(M1 @ x[b,:,n]) + b_lin,  M1 = -0.5*theta.
// R3 structure: weights are MFMA A-operands, x/P are B-operands.
//   GEMM1: D1[i,n] = sum_c M1[i,c] * x[c,n]   (B-frags of x loaded DIRECT from
//          global: col=n=lane&15 -> 64B segments, no staging LDS, no barrier)
//   relu -> f16 P stored to per-wave LDS [n][i] (b64 writes), read back as
//          B-frags for GEMM2 (b128 reads)  -- the only LDS use, one barrier.
//   GEMM2: D2[c,n] = sum_i W_lin[c,i] * P[i,n] + b_lin[c]
//          A = W_lin row-major as given; epilogue = contiguous float4 stores.
// mfma_f32_16x16x32_f16 layouts (HW-verified):
//   A[m=lane&15][k=quad*8+j]  B[col=lane&15][k=quad*8+j]  C/D: col=lane&15,row=quad*4+reg
// ---------------------------------------------------------------------------

typedef _Float16 v8h __attribute__((ext_vector_type(8)));
typedef __fp16   pk2 __attribute__((ext_vector_type(2)));  // cvt_pkrtz native type
typedef float    v4f __attribute__((ext_vector_type(4)));

union FragU { uint32_t u[4]; v8h h; };
union H2U   { pk2 h; uint32_t u; };

__device__ inline uint32_t pkf2(float a, float b) {
  H2U t; t.h = __builtin_amdgcn_cvt_pkrtz(a, b); return t.u;
}

__global__ void prep_weights(const float* __restrict__ theta,
                             const float* __restrict__ Wlin,
                             _Float16* __restrict__ M1h,
                             _Float16* __restrict__ Wh) {
  int t = blockIdx.x * 256 + threadIdx.x;
  if (t < Cc * Cc) {
    M1h[t] = (_Float16)(-0.5f * theta[t]);   // [i][c] row-major
    Wh[t]  = (_Float16)(Wlin[t]);            // [c][i] row-major (as given!)
  }
}

__global__ __launch_bounds__(256) void fused_mfma2(
    const float* __restrict__ x,      // [B, C, HW]
    const _Float16* __restrict__ M1h, // [64][64]
    const _Float16* __restrict__ Wh,  // [64][64]
    const float* __restrict__ blin,   // [64]
    float* __restrict__ out)          // [B, HW, C]
{
  // Per-wave private P tile: p2[wv][n(64)][i(64)] f16, row stride 72 (144B,
  // 16B-aligned rows). Reads 2-way banked (free), writes 4-way (16 instrs, ok).
  __shared__ __align__(16) _Float16 p2[4][64][72];

  const int tid = threadIdx.x;
  const int wv  = tid >> 6;
  const int lq  = tid & 15;
  const int q   = (tid & 63) >> 4;

  const int b   = blockIdx.x >> 6;                 // 64 blocks per batch
  const int n0  = (blockIdx.x & 63) * 256 + wv * 64; // wave's pixel base
  const float* xb = x + (size_t)b * Cc * HWc;

  // ---- A1 frags: M1 rows (A[m=i][k=c]) -- contiguous 16B, L1/L2-hot
  const v8h* M1v = (const v8h*)M1h;
  v8h a1[4][2];
#pragma unroll
  for (int it = 0; it < 4; ++it)
#pragma unroll
    for (int kt = 0; kt < 2; ++kt)
      a1[it][kt] = M1v[(it * 16 + lq) * 8 + kt * 4 + q];

  // ---- GEMM1 over 4 pixel sub-tiles; write P slices to this wave's LDS
#pragma unroll
  for (int nt = 0; nt < 4; ++nt) {
    const int n = n0 + nt * 16 + lq;               // this lane's pixel (col)
    // B1 frags direct from global: u[r] = pack(x[c0][n], x[c0+1][n]),
    // c0 = kt*32 + q*8 + 2r  (4 quads x 16 lq = 4 x 64B segments per load)
    FragU b1[2];
#pragma unroll
    for (int kt = 0; kt < 2; ++kt)
#pragma unroll
      for (int r = 0; r < 4; ++r) {
        const int c0 = kt * 32 + q * 8 + 2 * r;
        b1[kt].u[r] = pkf2(xb[(size_t)c0 * HWc + n],
                           xb[(size_t)(c0 + 1) * HWc + n]);
      }
    v4f acc[4];
#pragma unroll
    for (int it = 0; it < 4; ++it) {
      v4f a = {0.f, 0.f, 0.f, 0.f};
#pragma unroll
      for (int kt = 0; kt < 2; ++kt)
        a = __builtin_amdgcn_mfma_f32_16x16x32_f16(a1[it][kt], b1[kt].h, a, 0, 0, 0);
      acc[it] = a;
    }
    // relu -> f16, store to p2[n][i]: lane holds D1[i=it*16+4q+r][n=nt*16+lq]
    // -> 4 consecutive i per (it) = one 8B write at col it*16+4q
#pragma unroll
    for (int it = 0; it < 4; ++it) {
      uint2 w;
      w.x = pkf2(fmaxf(acc[it][0], 0.f), fmaxf(acc[it][1], 0.f));
      w.y = pkf2(fmaxf(acc[it][2], 0.f), fmaxf(acc[it][3], 0.f));
      *(uint2*)&p2[wv][nt * 16 + lq][it * 16 + 4 * q] = w;
    }
  }

  // ---- A2 frags: W_lin rows (A[m=c][k=i], row-major as given) + bias
  const v8h* Whv = (const v8h*)Wh;
  v8h a2[4][2];
#pragma unroll
  for (int ct = 0; ct < 4; ++ct)
#pragma unroll
    for (int kt = 0; kt < 2; ++kt)
      a2[ct][kt] = Whv[(ct * 16 + lq) * 8 + kt * 4 + q];

  float4 bias4[4];
#pragma unroll
  for (int ct = 0; ct < 4; ++ct)
    bias4[ct] = *(const float4*)(blin + ct * 16 + q * 4);

  __syncthreads();   // p2 write -> read (wave-private, but keep it simple/safe)

  // ---- GEMM2 + epilogue: contiguous float4 stores
#pragma unroll
  for (int nt = 0; nt < 4; ++nt) {
    const int n = n0 + nt * 16 + lq;
    // B2 frags: P[n][kt*32+q*8 .. +7] -- 16B contiguous LDS reads
    v8h b2[2];
#pragma unroll
    for (int kt = 0; kt < 2; ++kt)
      b2[kt] = *(const v8h*)&p2[wv][nt * 16 + lq][kt * 32 + q * 8];
#pragma unroll
    for (int ct = 0; ct < 4; ++ct) {
      v4f a = {bias4[ct].x, bias4[ct].y, bias4[ct].z, bias4[ct].w};
#pragma unroll
      for (int kt = 0; kt < 2; ++kt)
        a = __builtin_amdgcn_mfma_f32_16x16x32_f16(a2[ct][kt], b2[kt], a, 0, 0, 0);
      // D2: lane holds out[n][c = ct*16 + 4q + r], r=0..3 -> one float4 store
      *(v4f*)(out + ((size_t)b * HWc + n) * Cc + ct * 16 + q * 4) = a;
    }
  }
}

extern "C" void kernel_launch(void* const* d_in, const int* in_sizes, int n_in,
                              void* d_out, int out_size, void* d_ws, size_t ws_size,
                              hipStream_t stream) {
  const float* x     = (const float*)d_in[0];
  const float* theta = (const float*)d_in[1];
  const float* W_lin = (const float*)d_in[2];
  const float* b_lin = (const float*)d_in[3];
  float* out = (float*)d_out;

  _Float16* M1h = (_Float16*)d_ws;
  _Float16* Wh  = M1h + Cc * Cc;

  prep_weights<<<(Cc * Cc + 255) / 256, 256, 0, stream>>>(theta, W_lin, M1h, Wh);

  const int nblocks = Bc * HWc / 256;   // 2048
  fused_mfma2<<<nblocks, 256, 0, stream>>>(x, M1h, Wh, b_lin, out);
}